// Round 2
// baseline (1675.309 us; speedup 1.0000x reference)
//
#include <hip/hip_runtime.h>
#include <hip/hip_bf16.h>
#include <cstdint>

#define D_MODEL 1024
#define HEAD    64
#define SEQ     4096
#define BATCH   4
#define NROWS   (BATCH * SEQ)   // 16384

__device__ __forceinline__ float bl(unsigned u) { return __uint_as_float(u << 16); }
__device__ __forceinline__ float bh(unsigned u) { return __uint_as_float(u & 0xffff0000u); }

// out[row, h] = sum_d x[row, d] * w[d, h]   x:[NROWS,D] fp32, w:[D,H] fp32
// 16 threads per row, each computing 4 consecutive h. blockIdx.y selects q/k/v.
// qh kept fp32; kh/vh stored bf16 (halves attention read bandwidth).
__global__ __launch_bounds__(256) void proj_kernel(
    const float* __restrict__ xq, const float* __restrict__ xk,
    const float* __restrict__ xv,
    const float* __restrict__ wq, const float* __restrict__ wk,
    const float* __restrict__ wv,
    float* __restrict__ qh, __hip_bfloat16* __restrict__ kh,
    __hip_bfloat16* __restrict__ vh)
{
    const int which = blockIdx.y;
    const float* x = (which == 0) ? xq : (which == 1) ? xk : xv;
    const float* w = (which == 0) ? wq : (which == 1) ? wk : wv;

    int gid = blockIdx.x * 256 + threadIdx.x;     // 0 .. NROWS*16-1
    int row = gid >> 4;
    int h0  = (gid & 15) << 2;                    // 0,4,...,60

    const float* xr = x + (size_t)row * D_MODEL;
    const float* wp = w + h0;
    float a0 = 0.f, a1 = 0.f, a2 = 0.f, a3 = 0.f;

#pragma unroll 2
    for (int d = 0; d < D_MODEL; d += 4) {
        float4 xv4 = *(const float4*)(xr + d);
        float4 w0 = *(const float4*)(wp + (size_t)(d + 0) * HEAD);
        float4 w1 = *(const float4*)(wp + (size_t)(d + 1) * HEAD);
        float4 w2 = *(const float4*)(wp + (size_t)(d + 2) * HEAD);
        float4 w3 = *(const float4*)(wp + (size_t)(d + 3) * HEAD);
        a0 = fmaf(xv4.x, w0.x, a0); a1 = fmaf(xv4.x, w0.y, a1);
        a2 = fmaf(xv4.x, w0.z, a2); a3 = fmaf(xv4.x, w0.w, a3);
        a0 = fmaf(xv4.y, w1.x, a0); a1 = fmaf(xv4.y, w1.y, a1);
        a2 = fmaf(xv4.y, w1.z, a2); a3 = fmaf(xv4.y, w1.w, a3);
        a0 = fmaf(xv4.z, w2.x, a0); a1 = fmaf(xv4.z, w2.y, a1);
        a2 = fmaf(xv4.z, w2.z, a2); a3 = fmaf(xv4.z, w2.w, a3);
        a0 = fmaf(xv4.w, w3.x, a0); a1 = fmaf(xv4.w, w3.y, a1);
        a2 = fmaf(xv4.w, w3.z, a2); a3 = fmaf(xv4.w, w3.w, a3);
    }

    size_t o = (size_t)row * HEAD + h0;
    if (which == 0) {
        qh[o] = a0; qh[o + 1] = a1; qh[o + 2] = a2; qh[o + 3] = a3;
    } else {
        __hip_bfloat16* dst = (which == 1) ? kh : vh;
        dst[o]     = __float2bfloat16(a0);
        dst[o + 1] = __float2bfloat16(a1);
        dst[o + 2] = __float2bfloat16(a2);
        dst[o + 3] = __float2bfloat16(a3);
    }
}

// One wave per (batch, query) row. Lane t owns keys t, t+64, ... with a private
// online-softmax state (m, l, o[64]); butterfly-merged across lanes at the end.
__global__ __launch_bounds__(256, 2) void attn_kernel(
    const float* __restrict__ qh, const __hip_bfloat16* __restrict__ kh,
    const __hip_bfloat16* __restrict__ vh, float* __restrict__ out)
{
    int wid  = blockIdx.x * 4 + (threadIdx.x >> 6);   // 0..16383
    int lane = threadIdx.x & 63;
    int b    = wid >> 12;          // wid / 4096
    int qi   = wid & (SEQ - 1);

    const float* qr = qh + (size_t)wid * HEAD;
    const uint4* kb = (const uint4*)(kh + (size_t)b * SEQ * HEAD); // 8 uint4/key row
    const uint4* vb = (const uint4*)(vh + (size_t)b * SEQ * HEAD);

    float qv[HEAD];
#pragma unroll
    for (int h = 0; h < HEAD; ++h) qv[h] = qr[h];

    float m = -INFINITY, l = 0.f;
    float o[HEAD];
#pragma unroll
    for (int h = 0; h < HEAD; ++h) o[h] = 0.f;

    const int nk = qi + 1;
    for (int j0 = 0; j0 < nk; j0 += 64) {
        int j = j0 + lane;
        if (j < nk) {
            const uint4* krow = kb + (size_t)j * 8;
            float s = 0.f;
#pragma unroll
            for (int c = 0; c < 8; ++c) {
                uint4 u = krow[c];
                s = fmaf(qv[c * 8 + 0], bl(u.x), s);
                s = fmaf(qv[c * 8 + 1], bh(u.x), s);
                s = fmaf(qv[c * 8 + 2], bl(u.y), s);
                s = fmaf(qv[c * 8 + 3], bh(u.y), s);
                s = fmaf(qv[c * 8 + 4], bl(u.z), s);
                s = fmaf(qv[c * 8 + 5], bh(u.z), s);
                s = fmaf(qv[c * 8 + 6], bl(u.w), s);
                s = fmaf(qv[c * 8 + 7], bh(u.w), s);
            }
            s *= 0.125f;   // HEAD^-0.5
            float p;
            if (s > m) {
                float alpha = __expf(m - s);   // m=-inf on first hit -> alpha=0
                l *= alpha;
#pragma unroll
                for (int h = 0; h < HEAD; ++h) o[h] *= alpha;
                m = s;
                p = 1.f;
            } else {
                p = __expf(s - m);
            }
            l += p;
            const uint4* vrow = vb + (size_t)j * 8;
#pragma unroll
            for (int c = 0; c < 8; ++c) {
                uint4 u = vrow[c];
                o[c * 8 + 0] = fmaf(p, bl(u.x), o[c * 8 + 0]);
                o[c * 8 + 1] = fmaf(p, bh(u.x), o[c * 8 + 1]);
                o[c * 8 + 2] = fmaf(p, bl(u.y), o[c * 8 + 2]);
                o[c * 8 + 3] = fmaf(p, bh(u.y), o[c * 8 + 3]);
                o[c * 8 + 4] = fmaf(p, bl(u.z), o[c * 8 + 4]);
                o[c * 8 + 5] = fmaf(p, bh(u.z), o[c * 8 + 5]);
                o[c * 8 + 6] = fmaf(p, bl(u.w), o[c * 8 + 6]);
                o[c * 8 + 7] = fmaf(p, bh(u.w), o[c * 8 + 7]);
            }
        }
    }

    // Cross-lane merge. Lane 0 always processed key 0, so global max M is finite.
    float M = m;
#pragma unroll
    for (int off = 32; off > 0; off >>= 1) M = fmaxf(M, __shfl_xor(M, off));
    float sc = __expf(m - M);          // 0 for lanes that saw no keys
    l *= sc;
#pragma unroll
    for (int off = 32; off > 0; off >>= 1) l += __shfl_xor(l, off);

    float res = 0.f;
#pragma unroll
    for (int h = 0; h < HEAD; ++h) {
        float s = o[h] * sc;
#pragma unroll
        for (int off = 32; off > 0; off >>= 1) s += __shfl_xor(s, off);
        if (lane == h) res = s;
    }
    out[(size_t)wid * HEAD + lane] = res / l;
}

extern "C" void kernel_launch(void* const* d_in, const int* in_sizes, int n_in,
                              void* d_out, int out_size, void* d_ws, size_t ws_size,
                              hipStream_t stream) {
    const float* q  = (const float*)d_in[0];
    const float* k  = (const float*)d_in[1];
    const float* v  = (const float*)d_in[2];
    const float* wq = (const float*)d_in[3];
    const float* wk = (const float*)d_in[4];
    const float* wv = (const float*)d_in[5];

    // Workspace: qh fp32 (4 MB) | kh bf16 (2 MB) | vh bf16 (2 MB) = 8 MB
    float* qh = (float*)d_ws;
    __hip_bfloat16* kh = (__hip_bfloat16*)((char*)d_ws + (size_t)NROWS * HEAD * sizeof(float));
    __hip_bfloat16* vh = kh + (size_t)NROWS * HEAD;

    dim3 pgrid(NROWS * 16 / 256, 3);   // 1024 x 3
    proj_kernel<<<pgrid, 256, 0, stream>>>(q, k, v, wq, wk, wv, qh, kh, vh);

    attn_kernel<<<NROWS / 4, 256, 0, stream>>>(qh, kh, vh, (float*)d_out);
}

// Round 3
// 360.013 us; speedup vs baseline: 4.6535x; 4.6535x over previous
//
#include <hip/hip_runtime.h>
#include <hip/hip_bf16.h>
#include <cstdint>

#define D_MODEL 1024
#define HEAD    64
#define SEQ     4096
#define BATCH   4
#define NROWS   (BATCH * SEQ)   // 16384

typedef __attribute__((ext_vector_type(8))) short short8;   // 8 bf16 = 4 VGPRs (MFMA A/B frag)
typedef __attribute__((ext_vector_type(4))) float floatx4;  // MFMA C/D frag

__device__ __forceinline__ ushort f2bf(float f) {
    union { __hip_bfloat16 h; ushort u; } c;
    c.h = __float2bfloat16(f);
    return c.u;
}

// ---------------------------------------------------------------------------
// wt[which][n][k] = w_which[k][n] as bf16  (so MFMA B-frags are k-contiguous)
__global__ __launch_bounds__(256) void wprep_kernel(
    const float* __restrict__ wq, const float* __restrict__ wk,
    const float* __restrict__ wv, ushort* __restrict__ wt)
{
    int idx   = blockIdx.x * 256 + threadIdx.x;   // 0 .. 3*65536-1
    int which = idx >> 16;
    int r     = idx & 65535;                      // = k*64 + n (coalesced read)
    int k     = r >> 6;
    int n     = r & 63;
    const float* w = (which == 0) ? wq : (which == 1) ? wk : wv;
    wt[(size_t)(which * 64 + n) * D_MODEL + k] = f2bf(w[r]);
}

// ---------------------------------------------------------------------------
// y[m][n] = sum_k x[m][k] w[k][n] via mfma_f32_16x16x32_bf16.
// One wave (64 thr) per 16 rows. x staged fp32->bf16 in LDS (stride 72 keeps
// ds_read_b128 16B-aligned, rows spread across banks). B-frags: direct 16B
// global loads from pre-transposed wt (L1/L2-hot, 384 KB).
// which 0/1 -> row-major bf16 qh/kh; which 2 -> batch-transposed vt[b][h][s].
__global__ __launch_bounds__(64) void proj_kernel(
    const float* __restrict__ xq, const float* __restrict__ xk,
    const float* __restrict__ xv, const ushort* __restrict__ wt,
    ushort* __restrict__ qh, ushort* __restrict__ kh, ushort* __restrict__ vt)
{
    const int which = blockIdx.y;
    const float*  x = (which == 0) ? xq : (which == 1) ? xk : xv;
    const ushort* w = wt + (size_t)which * 64 * D_MODEL;

    const int row0 = blockIdx.x * 16;
    const int tid  = threadIdx.x;
    const int l16  = tid & 15;
    const int quad = tid >> 4;

    __shared__ ushort xs[16 * 72];

    floatx4 acc[4] = {};

    for (int kk = 0; kk < D_MODEL; kk += 64) {
        // stage 16 rows x 64 k (fp32 -> bf16)
#pragma unroll
        for (int i = 0; i < 4; ++i) {
            int idx = tid + i * 64;            // flat float4 index 0..255
            int r   = idx >> 4;
            int c4  = (idx & 15) << 2;
            float4 xv4 = *(const float4*)(x + (size_t)(row0 + r) * D_MODEL + kk + c4);
            uint2 pk = make_uint2((uint)f2bf(xv4.x) | ((uint)f2bf(xv4.y) << 16),
                                  (uint)f2bf(xv4.z) | ((uint)f2bf(xv4.w) << 16));
            *(uint2*)&xs[r * 72 + c4] = pk;
        }
        __syncthreads();

        short8 a0 = *(const short8*)&xs[l16 * 72 + quad * 8];        // k 0..31
        short8 a1 = *(const short8*)&xs[l16 * 72 + 32 + quad * 8];   // k 32..63

#pragma unroll
        for (int nt = 0; nt < 4; ++nt) {
            const ushort* wb = w + (size_t)(nt * 16 + l16) * D_MODEL + kk + quad * 8;
            short8 b0 = *(const short8*)wb;
            short8 b1 = *(const short8*)(wb + 32);
            acc[nt] = __builtin_amdgcn_mfma_f32_16x16x32_bf16(a0, b0, acc[nt], 0, 0, 0);
            acc[nt] = __builtin_amdgcn_mfma_f32_16x16x32_bf16(a1, b1, acc[nt], 0, 0, 0);
        }
        __syncthreads();
    }

    // C layout: col = l16, row = quad*4 + reg
    if (which < 2) {
        ushort* y = (which == 0) ? qh : kh;
#pragma unroll
        for (int nt = 0; nt < 4; ++nt) {
            int h = nt * 16 + l16;
#pragma unroll
            for (int r = 0; r < 4; ++r) {
                int gm = row0 + quad * 4 + r;
                y[(size_t)gm * HEAD + h] = f2bf(acc[nt][r]);
            }
        }
    } else {
        int gm0 = row0 + quad * 4;       // 4-aligned; batch-uniform within block
        int b   = gm0 >> 12;
        int s0  = gm0 & (SEQ - 1);
#pragma unroll
        for (int nt = 0; nt < 4; ++nt) {
            int h = nt * 16 + l16;
            uint2 pk = make_uint2((uint)f2bf(acc[nt][0]) | ((uint)f2bf(acc[nt][1]) << 16),
                                  (uint)f2bf(acc[nt][2]) | ((uint)f2bf(acc[nt][3]) << 16));
            *(uint2*)&vt[(size_t)(b * 64 + h) * SEQ + s0] = pk;
        }
    }
}

// ---------------------------------------------------------------------------
// MFMA flash attention. One wave per 16 query rows; 64-key tiles.
// QK^T: Q,K frags = direct 16B global loads (k-contiguous rows).
// Softmax in C-layout; row reductions = shfl_xor {1,2,4,8} in 16-lane groups.
// P -> per-wave private LDS (stride 72) -> A-frags for PV; V from vt[b][h][s].
__global__ __launch_bounds__(64) void attn_kernel(
    const ushort* __restrict__ qh, const ushort* __restrict__ kh,
    const ushort* __restrict__ vt, float* __restrict__ out)
{
    const int b    = blockIdx.x >> 8;          // 4 batches x 256 q-subtiles
    const int qs   = blockIdx.x & 255;
    const int q0   = qs * 16;
    const int tid  = threadIdx.x;
    const int l16  = tid & 15;
    const int quad = tid >> 4;

    __shared__ ushort Plds[16 * 72];

    const size_t qbase = ((size_t)b * SEQ + q0 + l16) * HEAD + quad * 8;
    short8 qa0 = *(const short8*)(qh + qbase);
    short8 qa1 = *(const short8*)(qh + qbase + 32);

    float m_[4], l_[4];
    floatx4 O[4] = {};
#pragma unroll
    for (int r = 0; r < 4; ++r) { m_[r] = -INFINITY; l_[r] = 0.f; }

    const int qrow_c = q0 + quad * 4;          // + reg = this lane's C rows
    const int nkt    = ((q0 + 15) >> 6) + 1;   // causal: key tiles 0..nkt-1

    for (int kt = 0; kt < nkt; ++kt) {
        const int k0 = kt * 64;

        // ---- S = Q K^T
        floatx4 sc[4];
#pragma unroll
        for (int nt = 0; nt < 4; ++nt) {
            const ushort* kb = kh + ((size_t)b * SEQ + k0 + nt * 16 + l16) * HEAD + quad * 8;
            short8 b0 = *(const short8*)kb;
            short8 b1 = *(const short8*)(kb + 32);
            floatx4 c = {};
            c = __builtin_amdgcn_mfma_f32_16x16x32_bf16(qa0, b0, c, 0, 0, 0);
            c = __builtin_amdgcn_mfma_f32_16x16x32_bf16(qa1, b1, c, 0, 0, 0);
            sc[nt] = c;
        }

        // ---- scale + causal mask (only the last tile can cross the diagonal)
        const bool domask = (k0 + 63 > q0);
        float s[4][4];
#pragma unroll
        for (int nt = 0; nt < 4; ++nt) {
            int kg = k0 + nt * 16 + l16;
#pragma unroll
            for (int r = 0; r < 4; ++r) {
                float v = sc[nt][r] * 0.125f;
                if (domask && kg > qrow_c + r) v = -INFINITY;
                s[nt][r] = v;
            }
        }

        // ---- online softmax
        float mn[4], alpha[4];
#pragma unroll
        for (int r = 0; r < 4; ++r) {
            float v = fmaxf(fmaxf(s[0][r], s[1][r]), fmaxf(s[2][r], s[3][r]));
            v = fmaxf(v, __shfl_xor(v, 1));
            v = fmaxf(v, __shfl_xor(v, 2));
            v = fmaxf(v, __shfl_xor(v, 4));
            v = fmaxf(v, __shfl_xor(v, 8));
            mn[r]    = fmaxf(m_[r], v);
            alpha[r] = __expf(m_[r] - mn[r]);   // first tile: exp(-inf)=0
        }

        float rs[4] = {0.f, 0.f, 0.f, 0.f};
#pragma unroll
        for (int nt = 0; nt < 4; ++nt) {
#pragma unroll
            for (int r = 0; r < 4; ++r) {
                float p = __expf(s[nt][r] - mn[r]);  // masked -> 0
                rs[r] += p;
                Plds[(quad * 4 + r) * 72 + nt * 16 + l16] = f2bf(p);
            }
        }
#pragma unroll
        for (int r = 0; r < 4; ++r) {
            float v = rs[r];
            v += __shfl_xor(v, 1);
            v += __shfl_xor(v, 2);
            v += __shfl_xor(v, 4);
            v += __shfl_xor(v, 8);
            l_[r] = l_[r] * alpha[r] + v;
            m_[r] = mn[r];
        }
#pragma unroll
        for (int nt = 0; nt < 4; ++nt)
#pragma unroll
            for (int r = 0; r < 4; ++r) O[nt][r] *= alpha[r];

        // ---- O += P V   (P via LDS round-trip to A-layout; single wave, no barrier)
        short8 pa0 = *(const short8*)&Plds[l16 * 72 + quad * 8];
        short8 pa1 = *(const short8*)&Plds[l16 * 72 + 32 + quad * 8];
#pragma unroll
        for (int nt = 0; nt < 4; ++nt) {
            const ushort* vb = vt + ((size_t)(b * 64 + nt * 16 + l16)) * SEQ + k0 + quad * 8;
            short8 v0 = *(const short8*)vb;
            short8 v1 = *(const short8*)(vb + 32);
            O[nt] = __builtin_amdgcn_mfma_f32_16x16x32_bf16(pa0, v0, O[nt], 0, 0, 0);
            O[nt] = __builtin_amdgcn_mfma_f32_16x16x32_bf16(pa1, v1, O[nt], 0, 0, 0);
        }
    }

    float inv[4];
#pragma unroll
    for (int r = 0; r < 4; ++r) inv[r] = 1.f / l_[r];
#pragma unroll
    for (int nt = 0; nt < 4; ++nt) {
        int h = nt * 16 + l16;
#pragma unroll
        for (int r = 0; r < 4; ++r)
            out[((size_t)b * SEQ + qrow_c + r) * HEAD + h] = O[nt][r] * inv[r];
    }
}

// ---------------------------------------------------------------------------
extern "C" void kernel_launch(void* const* d_in, const int* in_sizes, int n_in,
                              void* d_out, int out_size, void* d_ws, size_t ws_size,
                              hipStream_t stream) {
    const float* q  = (const float*)d_in[0];
    const float* k  = (const float*)d_in[1];
    const float* v  = (const float*)d_in[2];
    const float* wq = (const float*)d_in[3];
    const float* wk = (const float*)d_in[4];
    const float* wv = (const float*)d_in[5];

    // ws: qh bf16 (2MB) | kh bf16 (2MB) | vt bf16 [4][64][4096] (2MB) | wt (384KB)
    ushort* qh = (ushort*)d_ws;
    ushort* kh = qh + (size_t)NROWS * HEAD;
    ushort* vt = kh + (size_t)NROWS * HEAD;
    ushort* wt = vt + (size_t)NROWS * HEAD;

    wprep_kernel<<<768, 256, 0, stream>>>(wq, wk, wv, wt);

    dim3 pgrid(NROWS / 16, 3);   // 1024 x 3, 64-thread blocks
    proj_kernel<<<pgrid, 64, 0, stream>>>(q, k, v, wt, qh, kh, vt);

    attn_kernel<<<BATCH * (SEQ / 16), 64, 0, stream>>>(qh, kh, vt, (float*)d_out);
}

// Round 4
// 335.596 us; speedup vs baseline: 4.9920x; 1.0728x over previous
//
#include <hip/hip_runtime.h>
#include <hip/hip_bf16.h>
#include <cstdint>

#define D_MODEL 1024
#define HEAD    64
#define SEQ     4096
#define BATCH   4
#define NROWS   (BATCH * SEQ)   // 16384

typedef __attribute__((ext_vector_type(8))) short short8;   // 8 bf16 (MFMA A/B frag)
typedef __attribute__((ext_vector_type(4))) float floatx4;  // MFMA C/D frag

__device__ __forceinline__ ushort f2bf(float f) {
    union { __hip_bfloat16 h; ushort u; } c;
    c.h = __float2bfloat16(f);
    return c.u;
}
__device__ __forceinline__ uint pk2(float a, float b) {
    return (uint)f2bf(a) | ((uint)f2bf(b) << 16);
}

// ---------------------------------------------------------------------------
// wt[which][n][k] = w_which[k][n] as bf16  (MFMA B-frags k-contiguous)
__global__ __launch_bounds__(256) void wprep_kernel(
    const float* __restrict__ wq, const float* __restrict__ wk,
    const float* __restrict__ wv, ushort* __restrict__ wt)
{
    int idx   = blockIdx.x * 256 + threadIdx.x;   // 0 .. 3*65536-1
    int which = idx >> 16;
    int r     = idx & 65535;                      // = k*64 + n (coalesced read)
    int k     = r >> 6;
    int n     = r & 63;
    const float* w = (which == 0) ? wq : (which == 1) ? wk : wv;
    wt[(size_t)(which * 64 + n) * D_MODEL + k] = f2bf(w[r]);
}

// ---------------------------------------------------------------------------
// No-LDS MFMA projection: one wave per 16 rows x 64 cols. A-frags are direct
// 32B/lane x loads (row = l16, k = quad*8+j) converted fp32->bf16 in-register;
// B-frags from pre-transposed wt (L1/L2-hot). No barriers -> loads pipeline
// freely; 12 waves/CU hide HBM latency.
// which 0 -> qh (pre-scaled by 0.125!), 1 -> kh, 2 -> vt[b][h][s].
__global__ __launch_bounds__(64) void proj_kernel(
    const float* __restrict__ xq, const float* __restrict__ xk,
    const float* __restrict__ xv, const ushort* __restrict__ wt,
    ushort* __restrict__ qh, ushort* __restrict__ kh, ushort* __restrict__ vt)
{
    const int which = blockIdx.y;
    const float*  x = (which == 0) ? xq : (which == 1) ? xk : xv;
    const ushort* w = wt + (size_t)which * 64 * D_MODEL;

    const int row0 = blockIdx.x * 16;
    const int l16  = threadIdx.x & 15;
    const int quad = threadIdx.x >> 4;

    const float* xr = x + (size_t)(row0 + l16) * D_MODEL + quad * 8;

    floatx4 acc[4] = {};

#pragma unroll 2
    for (int kk = 0; kk < D_MODEL; kk += 64) {
        float4 xa0 = *(const float4*)(xr + kk);
        float4 xa1 = *(const float4*)(xr + kk + 4);
        float4 xb0 = *(const float4*)(xr + kk + 32);
        float4 xb1 = *(const float4*)(xr + kk + 36);
        union { short8 s; uint u[4]; } a0, a1;
        a0.u[0] = pk2(xa0.x, xa0.y); a0.u[1] = pk2(xa0.z, xa0.w);
        a0.u[2] = pk2(xa1.x, xa1.y); a0.u[3] = pk2(xa1.z, xa1.w);
        a1.u[0] = pk2(xb0.x, xb0.y); a1.u[1] = pk2(xb0.z, xb0.w);
        a1.u[2] = pk2(xb1.x, xb1.y); a1.u[3] = pk2(xb1.z, xb1.w);

#pragma unroll
        for (int nt = 0; nt < 4; ++nt) {
            const ushort* wb = w + (size_t)(nt * 16 + l16) * D_MODEL + kk + quad * 8;
            acc[nt] = __builtin_amdgcn_mfma_f32_16x16x32_bf16(a0.s, *(const short8*)wb, acc[nt], 0, 0, 0);
            acc[nt] = __builtin_amdgcn_mfma_f32_16x16x32_bf16(a1.s, *(const short8*)(wb + 32), acc[nt], 0, 0, 0);
        }
    }

    // C layout: col = l16 (-> h), row = quad*4 + r (-> row)
    if (which < 2) {
        ushort* y = (which == 0) ? qh : kh;
        const float sc = (which == 0) ? 0.125f : 1.0f;   // fold head_size^-0.5 into qh
#pragma unroll
        for (int nt = 0; nt < 4; ++nt) {
            int h = nt * 16 + l16;
#pragma unroll
            for (int r = 0; r < 4; ++r) {
                int gm = row0 + quad * 4 + r;
                y[(size_t)gm * HEAD + h] = f2bf(acc[nt][r] * sc);
            }
        }
    } else {
        int gm0 = row0 + quad * 4;       // 4-aligned; batch-uniform within block
        int b   = gm0 >> 12;
        int s0  = gm0 & (SEQ - 1);
#pragma unroll
        for (int nt = 0; nt < 4; ++nt) {
            int h = nt * 16 + l16;
            uint2 pk = make_uint2(pk2(acc[nt][0], acc[nt][1]), pk2(acc[nt][2], acc[nt][3]));
            *(uint2*)&vt[(size_t)(b * 64 + h) * SEQ + s0] = pk;
        }
    }
}

// ---------------------------------------------------------------------------
// MFMA flash attention, max-free softmax. One wave per 16 query rows.
// S^T = mfma(A=K, B=Q): C rows = keys (4 consecutive keys per reg quad),
// C cols = qrows. P packs 4 keys -> ds_write_b64; A-frag read ds_read_b128.
// l is a single lane-local scalar, reduced once at the end. K prefetched via
// register ping-pong; V issued at step top, consumed after exp/LDS section.
__global__ __launch_bounds__(64) void attn_kernel(
    const ushort* __restrict__ qh, const ushort* __restrict__ kh,
    const ushort* __restrict__ vt, float* __restrict__ out)
{
    const int b    = blockIdx.x >> 8;          // 4 batches x 256 q-subtiles
    const int q0   = (blockIdx.x & 255) * 16;
    const int l16  = threadIdx.x & 15;
    const int quad = threadIdx.x >> 4;

    __shared__ ushort Plds[16 * 72];

    const ushort* khb = kh + (size_t)b * SEQ * HEAD;
    const ushort* vtb = vt + (size_t)b * HEAD * SEQ;

    // Q B-frag (pre-scaled by 0.125): n = l16 -> qrow, k = quad*8+j -> h
    const size_t qbase = ((size_t)b * SEQ + q0 + l16) * HEAD + quad * 8;
    const short8 qa0 = *(const short8*)(qh + qbase);
    const short8 qa1 = *(const short8*)(qh + qbase + 32);

    floatx4 O[4] = {};
    float rs = 0.f;

    auto ldK = [&](int k0, short8* kf) {
#pragma unroll
        for (int nt = 0; nt < 4; ++nt) {
            const ushort* p = khb + (size_t)(k0 + nt * 16 + l16) * HEAD + quad * 8;
            kf[nt * 2]     = *(const short8*)p;
            kf[nt * 2 + 1] = *(const short8*)(p + 32);
        }
    };

    auto step = [&](const short8* kf, int k0, bool masked) {
        short8 vf[8];   // B[k=key][n=h]: 8 consecutive keys per lane from vt[h][s]
#pragma unroll
        for (int nt = 0; nt < 4; ++nt) {
            const ushort* p = vtb + (size_t)(nt * 16 + l16) * SEQ + k0 + quad * 8;
            vf[nt * 2]     = *(const short8*)p;
            vf[nt * 2 + 1] = *(const short8*)(p + 32);
        }
        floatx4 acc[4];
#pragma unroll
        for (int nt = 0; nt < 4; ++nt) {
            floatx4 c = {};
            c = __builtin_amdgcn_mfma_f32_16x16x32_bf16(kf[nt * 2],     qa0, c, 0, 0, 0);
            c = __builtin_amdgcn_mfma_f32_16x16x32_bf16(kf[nt * 2 + 1], qa1, c, 0, 0, 0);
            acc[nt] = c;   // S^T: row = key (quad*4+r), col = qrow (l16)
        }
#pragma unroll
        for (int nt = 0; nt < 4; ++nt) {
            union { ushort u[4]; uint2 w; } pk;
#pragma unroll
            for (int r = 0; r < 4; ++r) {
                float s = acc[nt][r];
                if (masked) {
                    int key = k0 + nt * 16 + quad * 4 + r;
                    if (key > q0 + l16) s = -3.0e38f;   // exp -> 0
                }
                float p = __expf(s);
                rs += p;
                pk.u[r] = f2bf(p);
            }
            *(uint2*)&Plds[l16 * 72 + nt * 16 + quad * 4] = pk.w;
        }
        short8 pa0 = *(const short8*)&Plds[l16 * 72 + quad * 8];        // P[qrow=l16][k]
        short8 pa1 = *(const short8*)&Plds[l16 * 72 + 32 + quad * 8];
#pragma unroll
        for (int nt = 0; nt < 4; ++nt) {
            O[nt] = __builtin_amdgcn_mfma_f32_16x16x32_bf16(pa0, vf[nt * 2],     O[nt], 0, 0, 0);
            O[nt] = __builtin_amdgcn_mfma_f32_16x16x32_bf16(pa1, vf[nt * 2 + 1], O[nt], 0, 0, 0);
        }
    };

    const int nkt = (q0 >> 6) + 1;
    short8 kA[8], kB[8];
    ldK(0, kA);
    bool useA = true;
    for (int kt = 0; kt < nkt - 1; ++kt) {
        if (useA) { ldK((kt + 1) * 64, kB); step(kA, kt * 64, false); }
        else      { ldK((kt + 1) * 64, kA); step(kB, kt * 64, false); }
        useA = !useA;
    }
    if (useA) step(kA, (nkt - 1) * 64, true);
    else      step(kB, (nkt - 1) * 64, true);

    // row sums: lane-local rs is partial for qrow = l16; sum over the 4 quads
    rs += __shfl_xor(rs, 16);
    rs += __shfl_xor(rs, 32);
    float linv = 1.f / rs;                       // lanes 0..15 hold l^-1 for qrow l16

    // O: col = l16 -> h (nt*16+l16), row = quad*4+r -> qrow
#pragma unroll
    for (int r = 0; r < 4; ++r) {
        float lr = __shfl(linv, quad * 4 + r);
        int qrow = q0 + quad * 4 + r;
#pragma unroll
        for (int nt = 0; nt < 4; ++nt)
            out[((size_t)b * SEQ + qrow) * HEAD + nt * 16 + l16] = O[nt][r] * lr;
    }
}

// ---------------------------------------------------------------------------
extern "C" void kernel_launch(void* const* d_in, const int* in_sizes, int n_in,
                              void* d_out, int out_size, void* d_ws, size_t ws_size,
                              hipStream_t stream) {
    const float* q  = (const float*)d_in[0];
    const float* k  = (const float*)d_in[1];
    const float* v  = (const float*)d_in[2];
    const float* wq = (const float*)d_in[3];
    const float* wk = (const float*)d_in[4];
    const float* wv = (const float*)d_in[5];

    // ws: qh bf16 (2MB) | kh bf16 (2MB) | vt bf16 [4][64][4096] (2MB) | wt (384KB)
    ushort* qh = (ushort*)d_ws;
    ushort* kh = qh + (size_t)NROWS * HEAD;
    ushort* vt = kh + (size_t)NROWS * HEAD;
    ushort* wt = vt + (size_t)NROWS * HEAD;

    wprep_kernel<<<768, 256, 0, stream>>>(wq, wk, wv, wt);

    dim3 pgrid(NROWS / 16, 3);   // 1024 x 3, single-wave blocks
    proj_kernel<<<pgrid, 64, 0, stream>>>(q, k, v, wt, qh, kh, vt);

    attn_kernel<<<BATCH * (SEQ / 16), 64, 0, stream>>>(qh, kh, vt, (float*)d_out);
}

// Round 5
// 328.040 us; speedup vs baseline: 5.1070x; 1.0230x over previous
//
#include <hip/hip_runtime.h>
#include <hip/hip_bf16.h>
#include <cstdint>

#define D_MODEL 1024
#define HEAD    64
#define SEQ     4096
#define BATCH   4
#define NROWS   (BATCH * SEQ)   // 16384

typedef __attribute__((ext_vector_type(8))) short short8;   // 8 bf16 (MFMA A/B frag)
typedef __attribute__((ext_vector_type(4))) float floatx4;  // MFMA C/D frag

__device__ __forceinline__ ushort f2bf(float f) {
    union { __hip_bfloat16 h; ushort u; } c;
    c.h = __float2bfloat16(f);
    return c.u;
}
__device__ __forceinline__ uint pk2(float a, float b) {
    return (uint)f2bf(a) | ((uint)f2bf(b) << 16);
}

// ---------------------------------------------------------------------------
// wt[which][n][k] = w_which[k][n] as bf16  (MFMA B-frags k-contiguous)
__global__ __launch_bounds__(256) void wprep_kernel(
    const float* __restrict__ wq, const float* __restrict__ wk,
    const float* __restrict__ wv, ushort* __restrict__ wt)
{
    int idx   = blockIdx.x * 256 + threadIdx.x;   // 0 .. 3*65536-1
    int which = idx >> 16;
    int r     = idx & 65535;                      // = k*64 + n (coalesced read)
    int k     = r >> 6;
    int n     = r & 63;
    const float* w = (which == 0) ? wq : (which == 1) ? wk : wv;
    wt[(size_t)(which * 64 + n) * D_MODEL + k] = f2bf(w[r]);
}

// ---------------------------------------------------------------------------
// MFMA projection, 2-wave k-split: wave w handles k in [w*512, w*512+512).
// fp32 partials merged via LDS (max-free linearity of the dot product).
// A-frags: direct 32B/lane x loads, 2-stage register pipeline (chunk kk+64 in
// flight during chunk kk's MFMAs). B-frags from pre-transposed wt (L2-hot).
// which 0 -> qh (pre-scaled by 0.125), 1 -> kh, 2 -> vt[b][h][s].
__global__ __launch_bounds__(128) void proj_kernel(
    const float* __restrict__ xq, const float* __restrict__ xk,
    const float* __restrict__ xv, const ushort* __restrict__ wt,
    ushort* __restrict__ qh, ushort* __restrict__ kh, ushort* __restrict__ vt)
{
    const int which = blockIdx.y;
    const float*  x = (which == 0) ? xq : (which == 1) ? xk : xv;
    const ushort* w = wt + (size_t)which * 64 * D_MODEL;

    const int row0 = blockIdx.x * 16;
    const int wv   = threadIdx.x >> 6;          // 0..1  (k-split half)
    const int ln   = threadIdx.x & 63;
    const int l16  = ln & 15;
    const int quad = ln >> 4;
    const int kofs = wv * 512;

    const float* xr = x + (size_t)(row0 + l16) * D_MODEL + kofs + quad * 8;

    __shared__ float mb[16][68];

    floatx4 acc[4] = {};

    float4 xb[4];
    xb[0] = *(const float4*)(xr + 0);
    xb[1] = *(const float4*)(xr + 4);
    xb[2] = *(const float4*)(xr + 32);
    xb[3] = *(const float4*)(xr + 36);

    for (int kk = 0; kk < 512; kk += 64) {
        int nk = (kk + 64 < 512) ? kk + 64 : kk;   // dummy reload on last iter
        float4 xn[4];
        xn[0] = *(const float4*)(xr + nk + 0);
        xn[1] = *(const float4*)(xr + nk + 4);
        xn[2] = *(const float4*)(xr + nk + 32);
        xn[3] = *(const float4*)(xr + nk + 36);

        union { short8 s; uint u[4]; } a0, a1;
        a0.u[0] = pk2(xb[0].x, xb[0].y); a0.u[1] = pk2(xb[0].z, xb[0].w);
        a0.u[2] = pk2(xb[1].x, xb[1].y); a0.u[3] = pk2(xb[1].z, xb[1].w);
        a1.u[0] = pk2(xb[2].x, xb[2].y); a1.u[1] = pk2(xb[2].z, xb[2].w);
        a1.u[2] = pk2(xb[3].x, xb[3].y); a1.u[3] = pk2(xb[3].z, xb[3].w);

#pragma unroll
        for (int nt = 0; nt < 4; ++nt) {
            const ushort* wb = w + (size_t)(nt * 16 + l16) * D_MODEL + kofs + kk + quad * 8;
            acc[nt] = __builtin_amdgcn_mfma_f32_16x16x32_bf16(a0.s, *(const short8*)wb, acc[nt], 0, 0, 0);
            acc[nt] = __builtin_amdgcn_mfma_f32_16x16x32_bf16(a1.s, *(const short8*)(wb + 32), acc[nt], 0, 0, 0);
        }
#pragma unroll
        for (int i = 0; i < 4; ++i) xb[i] = xn[i];
    }

    // merge the two k-halves
    if (wv == 1) {
#pragma unroll
        for (int nt = 0; nt < 4; ++nt)
#pragma unroll
            for (int r = 0; r < 4; ++r)
                mb[quad * 4 + r][nt * 16 + l16] = acc[nt][r];
    }
    __syncthreads();
    if (wv == 1) return;

#pragma unroll
    for (int nt = 0; nt < 4; ++nt)
#pragma unroll
        for (int r = 0; r < 4; ++r)
            acc[nt][r] += mb[quad * 4 + r][nt * 16 + l16];

    // C layout: col = l16 (-> h), row = quad*4 + r
    if (which < 2) {
        ushort* y = (which == 0) ? qh : kh;
        const float sc = (which == 0) ? 0.125f : 1.0f;   // fold head^-0.5 into qh
#pragma unroll
        for (int nt = 0; nt < 4; ++nt) {
            int h = nt * 16 + l16;
#pragma unroll
            for (int r = 0; r < 4; ++r)
                y[(size_t)(row0 + quad * 4 + r) * HEAD + h] = f2bf(acc[nt][r] * sc);
        }
    } else {
        int gm0 = row0 + quad * 4;
        int b   = gm0 >> 12;
        int s0  = gm0 & (SEQ - 1);
#pragma unroll
        for (int nt = 0; nt < 4; ++nt) {
            int h = nt * 16 + l16;
            uint2 pk = make_uint2(pk2(acc[nt][0], acc[nt][1]), pk2(acc[nt][2], acc[nt][3]));
            *(uint2*)&vt[(size_t)(b * 64 + h) * SEQ + s0] = pk;
        }
    }
}

// ---------------------------------------------------------------------------
// MFMA flash attention, max-free softmax, 4-wave K-split per 16-row q-tile.
// Wave w handles key tiles kt ≡ w (mod 4); partial (O, l) are ADDITIVE
// (no max, no rescale), merged once through LDS at the end.
// S^T = mfma(A=K, B=Q); P packed 4-keys-per-b64 into per-wave LDS, read back
// as A-frags for PV; V from pre-transposed vt[b][h][s].
__global__ __launch_bounds__(256, 4) void attn_kernel(
    const ushort* __restrict__ qh, const ushort* __restrict__ kh,
    const ushort* __restrict__ vt, float* __restrict__ out)
{
    const int b    = blockIdx.x >> 8;
    const int q0   = (blockIdx.x & 255) * 16;
    const int tid  = threadIdx.x;
    const int wv   = tid >> 6;           // wave 0..3
    const int ln   = tid & 63;
    const int l16  = ln & 15;
    const int quad = ln >> 4;

    __shared__ ushort Plds[4][16 * 72];   // per-wave private P staging
    __shared__ float  Obuf[4][16][68];    // per-wave partial O tiles
    __shared__ float  Lbuf[4][16];        // per-wave partial row sums

    const ushort* khb = kh + (size_t)b * SEQ * HEAD;
    const ushort* vtb = vt + (size_t)b * HEAD * SEQ;

    // Q B-frag (pre-scaled by 0.125): n = l16 -> qrow, k = quad*8+j -> h
    const size_t qbase = ((size_t)b * SEQ + q0 + l16) * HEAD + quad * 8;
    const short8 qa0 = *(const short8*)(qh + qbase);
    const short8 qa1 = *(const short8*)(qh + qbase + 32);

    floatx4 O[4] = {};
    float rs = 0.f;
    ushort* myP = Plds[wv];

    const int nkt = (q0 >> 6) + 1;

    for (int kt = wv; kt < nkt; kt += 4) {
        const int k0 = kt * 64;

        // V loads first, then K: QK's wait for K retires V too (both needed soon)
        short8 vf[8];
#pragma unroll
        for (int nt = 0; nt < 4; ++nt) {
            const ushort* vp = vtb + (size_t)(nt * 16 + l16) * SEQ + k0 + quad * 8;
            vf[nt * 2]     = *(const short8*)vp;
            vf[nt * 2 + 1] = *(const short8*)(vp + 32);
        }
        short8 kf[8];
#pragma unroll
        for (int nt = 0; nt < 4; ++nt) {
            const ushort* kp = khb + (size_t)(k0 + nt * 16 + l16) * HEAD + quad * 8;
            kf[nt * 2]     = *(const short8*)kp;
            kf[nt * 2 + 1] = *(const short8*)(kp + 32);
        }

        // S^T = K Q^T : C row = key (quad*4+r), col = qrow (l16)
        floatx4 acc[4];
#pragma unroll
        for (int nt = 0; nt < 4; ++nt) {
            floatx4 c = {};
            c = __builtin_amdgcn_mfma_f32_16x16x32_bf16(kf[nt * 2],     qa0, c, 0, 0, 0);
            c = __builtin_amdgcn_mfma_f32_16x16x32_bf16(kf[nt * 2 + 1], qa1, c, 0, 0, 0);
            acc[nt] = c;
        }

        const bool masked = (kt == nkt - 1);   // only the diagonal tile
#pragma unroll
        for (int nt = 0; nt < 4; ++nt) {
            union { ushort u[4]; uint2 w; } pk;
#pragma unroll
            for (int r = 0; r < 4; ++r) {
                float s = acc[nt][r];
                if (masked) {
                    int key = k0 + nt * 16 + quad * 4 + r;
                    if (key > q0 + l16) s = -3.0e38f;   // exp -> 0
                }
                float p = __expf(s);
                rs += p;
                pk.u[r] = f2bf(p);
            }
            *(uint2*)&myP[l16 * 72 + nt * 16 + quad * 4] = pk.w;
        }

        short8 pa0 = *(const short8*)&myP[l16 * 72 + quad * 8];
        short8 pa1 = *(const short8*)&myP[l16 * 72 + 32 + quad * 8];
#pragma unroll
        for (int nt = 0; nt < 4; ++nt) {
            O[nt] = __builtin_amdgcn_mfma_f32_16x16x32_bf16(pa0, vf[nt * 2],     O[nt], 0, 0, 0);
            O[nt] = __builtin_amdgcn_mfma_f32_16x16x32_bf16(pa1, vf[nt * 2 + 1], O[nt], 0, 0, 0);
        }
    }

    // partial row sums: sum over quads -> every lane has this wave's total for qrow=l16
    rs += __shfl_xor(rs, 16);
    rs += __shfl_xor(rs, 32);
    if (quad == 0) Lbuf[wv][l16] = rs;

#pragma unroll
    for (int nt = 0; nt < 4; ++nt)
#pragma unroll
        for (int r = 0; r < 4; ++r)
            Obuf[wv][quad * 4 + r][nt * 16 + l16] = O[nt][r];

    __syncthreads();

    // merge 4 wave-partials: thread -> (row = tid>>4, h0 = (tid&15)*4)
    const int row = tid >> 4;
    const int h0  = (tid & 15) * 4;
    float l = Lbuf[0][row] + Lbuf[1][row] + Lbuf[2][row] + Lbuf[3][row];
    float inv = 1.f / l;
    float4 o;
    o.x = (Obuf[0][row][h0 + 0] + Obuf[1][row][h0 + 0] + Obuf[2][row][h0 + 0] + Obuf[3][row][h0 + 0]) * inv;
    o.y = (Obuf[0][row][h0 + 1] + Obuf[1][row][h0 + 1] + Obuf[2][row][h0 + 1] + Obuf[3][row][h0 + 1]) * inv;
    o.z = (Obuf[0][row][h0 + 2] + Obuf[1][row][h0 + 2] + Obuf[2][row][h0 + 2] + Obuf[3][row][h0 + 2]) * inv;
    o.w = (Obuf[0][row][h0 + 3] + Obuf[1][row][h0 + 3] + Obuf[2][row][h0 + 3] + Obuf[3][row][h0 + 3]) * inv;
    *(float4*)&out[((size_t)b * SEQ + q0 + row) * HEAD + h0] = o;
}

// ---------------------------------------------------------------------------
extern "C" void kernel_launch(void* const* d_in, const int* in_sizes, int n_in,
                              void* d_out, int out_size, void* d_ws, size_t ws_size,
                              hipStream_t stream) {
    const float* q  = (const float*)d_in[0];
    const float* k  = (const float*)d_in[1];
    const float* v  = (const float*)d_in[2];
    const float* wq = (const float*)d_in[3];
    const float* wk = (const float*)d_in[4];
    const float* wv = (const float*)d_in[5];

    // ws: qh bf16 (2MB) | kh bf16 (2MB) | vt bf16 [4][64][4096] (2MB) | wt (384KB)
    ushort* qh = (ushort*)d_ws;
    ushort* kh = qh + (size_t)NROWS * HEAD;
    ushort* vt = kh + (size_t)NROWS * HEAD;
    ushort* wt = vt + (size_t)NROWS * HEAD;

    wprep_kernel<<<768, 256, 0, stream>>>(wq, wk, wv, wt);

    dim3 pgrid(NROWS / 16, 3);   // 1024 x 3, 128-thread (2-wave) blocks
    proj_kernel<<<pgrid, 128, 0, stream>>>(q, k, v, wt, qh, kh, vt);

    attn_kernel<<<BATCH * (SEQ / 16), 256, 0, stream>>>(qh, kh, vt, (float*)d_out);
}

// Round 6
// 281.797 us; speedup vs baseline: 5.9451x; 1.1641x over previous
//
#include <hip/hip_runtime.h>
#include <hip/hip_bf16.h>
#include <cstdint>

#define D_MODEL 1024
#define HEAD    64
#define SEQ     4096
#define BATCH   4
#define NROWS   (BATCH * SEQ)   // 16384

typedef __attribute__((ext_vector_type(8))) short short8;   // 8 bf16 (MFMA A/B frag)
typedef __attribute__((ext_vector_type(4))) float floatx4;  // MFMA C/D frag

__device__ __forceinline__ ushort f2bf(float f) {
    union { __hip_bfloat16 h; ushort u; } c;
    c.h = __float2bfloat16(f);
    return c.u;
}
__device__ __forceinline__ uint pk2(float a, float b) {
    return (uint)f2bf(a) | ((uint)f2bf(b) << 16);
}

// ---------------------------------------------------------------------------
// wt[which][n][k] = w_which[k][n] bf16, via LDS tile transpose (coalesced both ways).
// Grid (D_MODEL/64, 3), 256 threads.
__global__ __launch_bounds__(256) void wprep_kernel(
    const float* __restrict__ wq, const float* __restrict__ wk,
    const float* __restrict__ wv, ushort* __restrict__ wt)
{
    const int which = blockIdx.y;
    const int k0    = blockIdx.x * 64;
    const float* w  = (which == 0) ? wq : (which == 1) ? wk : wv;
    const int tid   = threadIdx.x;

    __shared__ ushort lds[64][65];

#pragma unroll
    for (int i = 0; i < 16; ++i) {
        int idx = tid + 256 * i;          // 0..4095
        int kl  = idx >> 6;
        int n   = idx & 63;
        lds[n][kl] = f2bf(w[(size_t)(k0 + kl) * 64 + n]);   // coalesced read
    }
    __syncthreads();
#pragma unroll
    for (int i = 0; i < 16; ++i) {
        int idx = tid + 256 * i;
        int n   = idx >> 6;
        int kl  = idx & 63;
        wt[(size_t)(which * 64 + n) * D_MODEL + k0 + kl] = lds[n][kl];  // coalesced write
    }
}

// ---------------------------------------------------------------------------
// MFMA projection, single wave per 16 rows, register double-buffer on BOTH
// x (4 float4) and w (8 short8): chunk kk's MFMAs wait on loads issued a full
// iteration earlier. 3072 blocks -> 12 waves/CU.
// which 0 -> qh (pre-scaled by 0.125), 1 -> kh, 2 -> vt[b][h][s].
__global__ __launch_bounds__(64) void proj_kernel(
    const float* __restrict__ xq, const float* __restrict__ xk,
    const float* __restrict__ xv, const ushort* __restrict__ wt,
    ushort* __restrict__ qh, ushort* __restrict__ kh, ushort* __restrict__ vt)
{
    const int which = blockIdx.y;
    const float*  x = (which == 0) ? xq : (which == 1) ? xk : xv;
    const ushort* w = wt + (size_t)which * 64 * D_MODEL;

    const int row0 = blockIdx.x * 16;
    const int l16  = threadIdx.x & 15;
    const int quad = threadIdx.x >> 4;

    const float* xr = x + (size_t)(row0 + l16) * D_MODEL + quad * 8;
    const ushort* wr[4];
#pragma unroll
    for (int nt = 0; nt < 4; ++nt)
        wr[nt] = w + (size_t)(nt * 16 + l16) * D_MODEL + quad * 8;

    floatx4 acc[4] = {};

    float4 xc[4];
    short8 wc[8];
    xc[0] = *(const float4*)(xr + 0);  xc[1] = *(const float4*)(xr + 4);
    xc[2] = *(const float4*)(xr + 32); xc[3] = *(const float4*)(xr + 36);
#pragma unroll
    for (int nt = 0; nt < 4; ++nt) {
        wc[nt * 2]     = *(const short8*)(wr[nt]);
        wc[nt * 2 + 1] = *(const short8*)(wr[nt] + 32);
    }

    for (int kk = 0; kk < D_MODEL; kk += 64) {
        const int nk = (kk + 64 < D_MODEL) ? kk + 64 : kk;   // dummy on last iter
        float4 xn[4];
        short8 wn[8];
        xn[0] = *(const float4*)(xr + nk + 0);  xn[1] = *(const float4*)(xr + nk + 4);
        xn[2] = *(const float4*)(xr + nk + 32); xn[3] = *(const float4*)(xr + nk + 36);
#pragma unroll
        for (int nt = 0; nt < 4; ++nt) {
            wn[nt * 2]     = *(const short8*)(wr[nt] + nk);
            wn[nt * 2 + 1] = *(const short8*)(wr[nt] + nk + 32);
        }

        union { short8 s; uint u[4]; } a0, a1;
        a0.u[0] = pk2(xc[0].x, xc[0].y); a0.u[1] = pk2(xc[0].z, xc[0].w);
        a0.u[2] = pk2(xc[1].x, xc[1].y); a0.u[3] = pk2(xc[1].z, xc[1].w);
        a1.u[0] = pk2(xc[2].x, xc[2].y); a1.u[1] = pk2(xc[2].z, xc[2].w);
        a1.u[2] = pk2(xc[3].x, xc[3].y); a1.u[3] = pk2(xc[3].z, xc[3].w);

#pragma unroll
        for (int nt = 0; nt < 4; ++nt) {
            acc[nt] = __builtin_amdgcn_mfma_f32_16x16x32_bf16(a0.s, wc[nt * 2],     acc[nt], 0, 0, 0);
            acc[nt] = __builtin_amdgcn_mfma_f32_16x16x32_bf16(a1.s, wc[nt * 2 + 1], acc[nt], 0, 0, 0);
        }
#pragma unroll
        for (int i = 0; i < 4; ++i) xc[i] = xn[i];
#pragma unroll
        for (int i = 0; i < 8; ++i) wc[i] = wn[i];
    }

    // C layout: col = l16 (-> h), row = quad*4 + r
    if (which < 2) {
        ushort* y = (which == 0) ? qh : kh;
        const float sc = (which == 0) ? 0.125f : 1.0f;   // fold head^-0.5 into qh
#pragma unroll
        for (int nt = 0; nt < 4; ++nt) {
            int h = nt * 16 + l16;
#pragma unroll
            for (int r = 0; r < 4; ++r)
                y[(size_t)(row0 + quad * 4 + r) * HEAD + h] = f2bf(acc[nt][r] * sc);
        }
    } else {
        int gm0 = row0 + quad * 4;
        int b   = gm0 >> 12;
        int s0  = gm0 & (SEQ - 1);
#pragma unroll
        for (int nt = 0; nt < 4; ++nt) {
            int h = nt * 16 + l16;
            uint2 pk = make_uint2(pk2(acc[nt][0], acc[nt][1]), pk2(acc[nt][2], acc[nt][3]));
            *(uint2*)&vt[(size_t)(b * 64 + h) * SEQ + s0] = pk;
        }
    }
}

// ---------------------------------------------------------------------------
// MFMA flash attention, max-free softmax. Block = two PAIRED q-tiles
// (i, 255-i) -> equal work per block (65-66 key-tiles), grid 512, no tail.
// 4 waves K-split each tile (kt ≡ wave mod 4); partial (O,l) additive.
// Each wave interleaves the two tiles' step-chains phase by phase, so every
// stall in chain A is covered by independent work from chain B.
__global__ __launch_bounds__(256, 2) void attn_kernel(
    const ushort* __restrict__ qh, const ushort* __restrict__ kh,
    const ushort* __restrict__ vt, float* __restrict__ out)
{
    const int b    = blockIdx.x >> 7;          // 4 batches x 128 tile-pairs
    const int i    = blockIdx.x & 127;
    const int qsA  = i, qsB = 255 - i;
    const int q0A  = qsA * 16, q0B = qsB * 16;
    const int nA   = (qsA >> 2) + 1;           // key tiles for tile A
    const int nB   = (qsB >> 2) + 1;
    const int tid  = threadIdx.x;
    const int wv   = tid >> 6;
    const int ln   = tid & 63;
    const int l16  = ln & 15;
    const int quad = ln >> 4;

    __shared__ ushort PA[4][16 * 72];
    __shared__ ushort PB[4][16 * 72];
    __shared__ float  Obuf[4][16][68];
    __shared__ float  Lbuf[4][16];

    const ushort* khb = kh + (size_t)b * SEQ * HEAD;
    const ushort* vtb = vt + (size_t)b * HEAD * SEQ;

    // Q B-frags (pre-scaled): n = l16 -> qrow, k = quad*8+j -> h
    const size_t qbA = ((size_t)b * SEQ + q0A + l16) * HEAD + quad * 8;
    const size_t qbB = ((size_t)b * SEQ + q0B + l16) * HEAD + quad * 8;
    const short8 qA0 = *(const short8*)(qh + qbA);
    const short8 qA1 = *(const short8*)(qh + qbA + 32);
    const short8 qB0 = *(const short8*)(qh + qbB);
    const short8 qB1 = *(const short8*)(qh + qbB + 32);

    floatx4 OA[4] = {}, OB[4] = {};
    float rsA = 0.f, rsB = 0.f;
    ushort* myPA = PA[wv];
    ushort* myPB = PB[wv];

    const int cA = (nA > wv) ? (((nA - 1 - wv) >> 2) + 1) : 0;   // steps for A
    const int cB = ((nB - 1 - wv) >> 2) + 1;                     // nB >= 33 > wv
    const int steps = (cA > cB) ? cA : cB;

    for (int s = 0; s < steps; ++s) {
        const int ktA = wv + 4 * s, ktB = wv + 4 * s;
        const bool doA = s < cA, doB = s < cB;
        const int k0A = ktA * 64, k0B = ktB * 64;

        short8 kfA[8], vfA[8], kfB[8], vfB[8];
        if (doA) {
#pragma unroll
            for (int nt = 0; nt < 4; ++nt) {
                const ushort* vp = vtb + (size_t)(nt * 16 + l16) * SEQ + k0A + quad * 8;
                vfA[nt * 2] = *(const short8*)vp; vfA[nt * 2 + 1] = *(const short8*)(vp + 32);
                const ushort* kp = khb + (size_t)(k0A + nt * 16 + l16) * HEAD + quad * 8;
                kfA[nt * 2] = *(const short8*)kp; kfA[nt * 2 + 1] = *(const short8*)(kp + 32);
            }
        }
        if (doB) {
#pragma unroll
            for (int nt = 0; nt < 4; ++nt) {
                const ushort* vp = vtb + (size_t)(nt * 16 + l16) * SEQ + k0B + quad * 8;
                vfB[nt * 2] = *(const short8*)vp; vfB[nt * 2 + 1] = *(const short8*)(vp + 32);
                const ushort* kp = khb + (size_t)(k0B + nt * 16 + l16) * HEAD + quad * 8;
                kfB[nt * 2] = *(const short8*)kp; kfB[nt * 2 + 1] = *(const short8*)(kp + 32);
            }
        }

        // S^T = K Q^T : C row = key (quad*4+r), col = qrow (l16)
        floatx4 aA[4], aB[4];
        if (doA) {
#pragma unroll
            for (int nt = 0; nt < 4; ++nt) {
                floatx4 c = {};
                c = __builtin_amdgcn_mfma_f32_16x16x32_bf16(kfA[nt * 2],     qA0, c, 0, 0, 0);
                c = __builtin_amdgcn_mfma_f32_16x16x32_bf16(kfA[nt * 2 + 1], qA1, c, 0, 0, 0);
                aA[nt] = c;
            }
        }
        if (doB) {
#pragma unroll
            for (int nt = 0; nt < 4; ++nt) {
                floatx4 c = {};
                c = __builtin_amdgcn_mfma_f32_16x16x32_bf16(kfB[nt * 2],     qB0, c, 0, 0, 0);
                c = __builtin_amdgcn_mfma_f32_16x16x32_bf16(kfB[nt * 2 + 1], qB1, c, 0, 0, 0);
                aB[nt] = c;
            }
        }

        if (doA) {
            const bool masked = (ktA == nA - 1);
#pragma unroll
            for (int nt = 0; nt < 4; ++nt) {
                union { ushort u[4]; uint2 w; } pk;
#pragma unroll
                for (int r = 0; r < 4; ++r) {
                    float sv = aA[nt][r];
                    if (masked && (k0A + nt * 16 + quad * 4 + r > q0A + l16)) sv = -3.0e38f;
                    float p = __expf(sv);
                    rsA += p;
                    pk.u[r] = f2bf(p);
                }
                *(uint2*)&myPA[l16 * 72 + nt * 16 + quad * 4] = pk.w;
            }
        }
        if (doB) {
            const bool masked = (ktB == nB - 1);
#pragma unroll
            for (int nt = 0; nt < 4; ++nt) {
                union { ushort u[4]; uint2 w; } pk;
#pragma unroll
                for (int r = 0; r < 4; ++r) {
                    float sv = aB[nt][r];
                    if (masked && (k0B + nt * 16 + quad * 4 + r > q0B + l16)) sv = -3.0e38f;
                    float p = __expf(sv);
                    rsB += p;
                    pk.u[r] = f2bf(p);
                }
                *(uint2*)&myPB[l16 * 72 + nt * 16 + quad * 4] = pk.w;
            }
        }

        if (doA) {
            short8 p0 = *(const short8*)&myPA[l16 * 72 + quad * 8];
            short8 p1 = *(const short8*)&myPA[l16 * 72 + 32 + quad * 8];
#pragma unroll
            for (int nt = 0; nt < 4; ++nt) {
                OA[nt] = __builtin_amdgcn_mfma_f32_16x16x32_bf16(p0, vfA[nt * 2],     OA[nt], 0, 0, 0);
                OA[nt] = __builtin_amdgcn_mfma_f32_16x16x32_bf16(p1, vfA[nt * 2 + 1], OA[nt], 0, 0, 0);
            }
        }
        if (doB) {
            short8 p0 = *(const short8*)&myPB[l16 * 72 + quad * 8];
            short8 p1 = *(const short8*)&myPB[l16 * 72 + 32 + quad * 8];
#pragma unroll
            for (int nt = 0; nt < 4; ++nt) {
                OB[nt] = __builtin_amdgcn_mfma_f32_16x16x32_bf16(p0, vfB[nt * 2],     OB[nt], 0, 0, 0);
                OB[nt] = __builtin_amdgcn_mfma_f32_16x16x32_bf16(p1, vfB[nt * 2 + 1], OB[nt], 0, 0, 0);
            }
        }
    }

    // ---- merge tile A ----
    rsA += __shfl_xor(rsA, 16); rsA += __shfl_xor(rsA, 32);
    if (quad == 0) Lbuf[wv][l16] = rsA;
#pragma unroll
    for (int nt = 0; nt < 4; ++nt)
#pragma unroll
        for (int r = 0; r < 4; ++r)
            Obuf[wv][quad * 4 + r][nt * 16 + l16] = OA[nt][r];
    __syncthreads();
    {
        const int row = tid >> 4, h0 = (tid & 15) * 4;
        float l = Lbuf[0][row] + Lbuf[1][row] + Lbuf[2][row] + Lbuf[3][row];
        float inv = 1.f / l;
        float4 o;
        o.x = (Obuf[0][row][h0+0] + Obuf[1][row][h0+0] + Obuf[2][row][h0+0] + Obuf[3][row][h0+0]) * inv;
        o.y = (Obuf[0][row][h0+1] + Obuf[1][row][h0+1] + Obuf[2][row][h0+1] + Obuf[3][row][h0+1]) * inv;
        o.z = (Obuf[0][row][h0+2] + Obuf[1][row][h0+2] + Obuf[2][row][h0+2] + Obuf[3][row][h0+2]) * inv;
        o.w = (Obuf[0][row][h0+3] + Obuf[1][row][h0+3] + Obuf[2][row][h0+3] + Obuf[3][row][h0+3]) * inv;
        *(float4*)&out[((size_t)b * SEQ + q0A + row) * HEAD + h0] = o;
    }
    __syncthreads();

    // ---- merge tile B ----
    rsB += __shfl_xor(rsB, 16); rsB += __shfl_xor(rsB, 32);
    if (quad == 0) Lbuf[wv][l16] = rsB;
#pragma unroll
    for (int nt = 0; nt < 4; ++nt)
#pragma unroll
        for (int r = 0; r < 4; ++r)
            Obuf[wv][quad * 4 + r][nt * 16 + l16] = OB[nt][r];
    __syncthreads();
    {
        const int row = tid >> 4, h0 = (tid & 15) * 4;
        float l = Lbuf[0][row] + Lbuf[1][row] + Lbuf[2][row] + Lbuf[3][row];
        float inv = 1.f / l;
        float4 o;
        o.x = (Obuf[0][row][h0+0] + Obuf[1][row][h0+0] + Obuf[2][row][h0+0] + Obuf[3][row][h0+0]) * inv;
        o.y = (Obuf[0][row][h0+1] + Obuf[1][row][h0+1] + Obuf[2][row][h0+1] + Obuf[3][row][h0+1]) * inv;
        o.z = (Obuf[0][row][h0+2] + Obuf[1][row][h0+2] + Obuf[2][row][h0+2] + Obuf[3][row][h0+2]) * inv;
        o.w = (Obuf[0][row][h0+3] + Obuf[1][row][h0+3] + Obuf[2][row][h0+3] + Obuf[3][row][h0+3]) * inv;
        *(float4*)&out[((size_t)b * SEQ + q0B + row) * HEAD + h0] = o;
    }
}

// ---------------------------------------------------------------------------
extern "C" void kernel_launch(void* const* d_in, const int* in_sizes, int n_in,
                              void* d_out, int out_size, void* d_ws, size_t ws_size,
                              hipStream_t stream) {
    const float* q  = (const float*)d_in[0];
    const float* k  = (const float*)d_in[1];
    const float* v  = (const float*)d_in[2];
    const float* wq = (const float*)d_in[3];
    const float* wk = (const float*)d_in[4];
    const float* wv = (const float*)d_in[5];

    // ws: qh bf16 (2MB) | kh bf16 (2MB) | vt bf16 [4][64][4096] (2MB) | wt (384KB)
    ushort* qh = (ushort*)d_ws;
    ushort* kh = qh + (size_t)NROWS * HEAD;
    ushort* vt = kh + (size_t)NROWS * HEAD;
    ushort* wt = vt + (size_t)NROWS * HEAD;

    dim3 wgrid(D_MODEL / 64, 3);
    wprep_kernel<<<wgrid, 256, 0, stream>>>(wq, wk, wv, wt);

    dim3 pgrid(NROWS / 16, 3);   // 1024 x 3, single-wave blocks
    proj_kernel<<<pgrid, 64, 0, stream>>>(q, k, v, wt, qh, kh, vt);

    attn_kernel<<<BATCH * 128, 256, 0, stream>>>(qh, kh, vt, (float*)d_out);
}